// Round 8
// baseline (254.775 us; speedup 1.0000x reference)
//
#include <hip/hip_runtime.h>
#include <hip/hip_fp16.h>

// ---------------------------------------------------------------------------
// GCN 2-layer forward on MI355X.
//   prepA: gemm1-half (rows < RA, hs1 = fp16(X@W1), UNSCALED) || bscatter.
//   prepB: bfinal (CSR finalize) || gemm1-half (rows >= RA) -- bfinal depends
//          only on bscatter, not gemm1, so the second gemm1 half hides under
//          it (R7 only hid min(gemm1, bscatter)).
//   FUSED agg1+gemm2 (R2 layout, KS=136 pad -- R6 proved swizzle slower):
//     - dinv applied AT GATHER (fmac); self = di^2*h_i via acc-init.
//     - ssrc loaded as dwordx4 (R7 lesson: gather is request-rate-sensitive;
//       12->9 VMEM inst/4-edge iter).
//     - per-wave 16x64x128 MFMA, wave-local LDS + lgkmcnt(0), no block
//       barrier after gather. __launch_bounds__(512,8) (R5: (512,4) PINS
//       occupancy at 4 waves/EU).
//   agg2: out = dinv*(gather+self)+b2, ssrc dwordx4 too.
//   Gather FETCH = 8 XCDs x table = structural floor (random graph).
// ---------------------------------------------------------------------------

#define KDIM 128
#define BSHIFT 9
#define BSIZE 512
#define ECHUNK 2048
#define CAP 10240              // per-bucket capacity; mean 8192, sigma~90 -> 22σ
#define PACK_SHIFT 20
#define PACK_MASK ((1u << PACK_SHIFT) - 1)

typedef _Float16 h8 __attribute__((ext_vector_type(8)));
typedef float f4v __attribute__((ext_vector_type(4)));

typedef int int4v __attribute__((ext_vector_type(4)));

__device__ inline h8 pack8(float4 u, float4 v) {
    h8 r;
    r[0] = (_Float16)u.x; r[1] = (_Float16)u.y; r[2] = (_Float16)u.z; r[3] = (_Float16)u.w;
    r[4] = (_Float16)v.x; r[5] = (_Float16)v.y; r[6] = (_Float16)v.z; r[7] = (_Float16)v.w;
    return r;
}

// ---- prepA: gemm1 rows [0, GB*128) || bscatter ----------------------------
// Role by blockIdx parity (interleaved for co-residency); 34816 B shared buf.

__launch_bounds__(256) __global__
void prepA_kernel(const float* __restrict__ X, const float* __restrict__ W,
                  _Float16* __restrict__ outh,
                  const int* __restrict__ src, const int* __restrict__ dst,
                  int* __restrict__ ecnt, unsigned int* __restrict__ packed_out,
                  int N, int E, int NB, int GB, int EB) {
    __shared__ __align__(16) char shbuf[34816];

    const int t = threadIdx.x;
    const int tm = 2 * min(GB, EB);
    bool isg;
    int bid;
    if ((int)blockIdx.x < tm) {
        isg = !(blockIdx.x & 1);
        bid = blockIdx.x >> 1;
    } else {
        bid = (tm >> 1) + ((int)blockIdx.x - tm);
        isg = (GB > EB);
    }

    if (isg) {
        // ---------------- gemm1 role: 128 rows x 128 cols --------------------
        constexpr int K = KDIM;       // 128
        constexpr int KS = K + 8;     // 136
        constexpr int DOUT = 128;
        constexpr int NT = DOUT / 16; // 8
        _Float16* Wl = (_Float16*)shbuf;

        const int wave = t >> 6;
        const int lane = t & 63;
        const int l15 = lane & 15;
        const int quad = lane >> 4;

        // stage W (fp32 [K][DOUT] row-major) -> Wl fp16 n-major [n][k]
#pragma unroll
        for (int i = t; i < DOUT * (K / 4); i += 256) {
            int n = i & (DOUT - 1);
            int kg = i >> 7;       // 0..31
            union { _Float16 h[4]; uint2 u; } tmp;
#pragma unroll
            for (int j = 0; j < 4; j++)
                tmp.h[j] = (_Float16)W[(size_t)(kg * 4 + j) * DOUT + n];
            *(uint2*)(&Wl[n * KS + kg * 4]) = tmp.u;
        }
        __syncthreads();

        const int rowbase = bid * 128;
        const int row0 = rowbase + wave * 32 + l15;
        const int row1 = row0 + 16;
        const int rc0 = min(row0, N - 1);
        const int rc1 = min(row1, N - 1);

        f4v acc[2][NT];
#pragma unroll
        for (int r = 0; r < 2; r++)
#pragma unroll
            for (int ct = 0; ct < NT; ct++) acc[r][ct] = (f4v)0.0f;

#pragma unroll
        for (int kc = 0; kc < K; kc += 32) {
            const int kof = kc + quad * 8;
            const float* p0 = X + (size_t)rc0 * K + kof;
            const float* p1 = X + (size_t)rc1 * K + kof;
            h8 a0 = pack8(*(const float4*)p0, *(const float4*)(p0 + 4));
            h8 a1 = pack8(*(const float4*)p1, *(const float4*)(p1 + 4));
#pragma unroll
            for (int ct = 0; ct < NT; ct++) {
                h8 b = *(const h8*)(&Wl[(size_t)(ct * 16 + l15) * KS + kof]);
                acc[0][ct] = __builtin_amdgcn_mfma_f32_16x16x32_f16(a0, b, acc[0][ct], 0, 0, 0);
                acc[1][ct] = __builtin_amdgcn_mfma_f32_16x16x32_f16(a1, b, acc[1][ct], 0, 0, 0);
            }
        }

#pragma unroll
        for (int r = 0; r < 2; r++) {
            const int rb = rowbase + wave * 32 + r * 16 + quad * 4;
#pragma unroll
            for (int g = 0; g < 4; g++) {
                int row = rb + g;
                if (row < N) {
                    _Float16* op = outh + (size_t)row * DOUT + l15;
#pragma unroll
                    for (int ct = 0; ct < NT; ct++)
                        op[ct * 16] = (_Float16)acc[r][ct][g];   // unscaled
                }
            }
        }
    } else {
        // ---------------- bscatter role: 2048-edge chunk ---------------------
        int* lcnt = (int*)shbuf;                          // [256]
        int* lexc = lcnt + 256;                           // [256]
        int* lbase = lexc + 256;                          // [256]
        unsigned int* lpacked = (unsigned int*)(lbase + 256);        // [2048]
        unsigned char* lbslot = (unsigned char*)(lpacked + ECHUNK);  // [2048]

        lcnt[t] = 0;
        __syncthreads();

        const int base = bid * ECHUNK;
        const int cnt = min(ECHUNK, E - base);

#pragma unroll
        for (int j = 0; j < ECHUNK / 256; j++) {
            int e = base + j * 256 + t;
            if (e < E) atomicAdd(&lcnt[dst[e] >> BSHIFT], 1);
        }
        __syncthreads();

        lexc[t] = lcnt[t];
        __syncthreads();
        for (int off = 1; off < 256; off <<= 1) {
            int x = (t >= off) ? lexc[t - off] : 0;
            __syncthreads();
            if (t >= off) lexc[t] += x;
            __syncthreads();
        }
        lexc[t] = lexc[t] - lcnt[t];            // own slot only: safe

        if (t < NB && lcnt[t]) lbase[t] = t * CAP + atomicAdd(&ecnt[t], lcnt[t]);
        __syncthreads();
        lcnt[t] = lexc[t];                      // local placement cursor
        __syncthreads();

#pragma unroll
        for (int j = 0; j < ECHUNK / 256; j++) {
            int e = base + j * 256 + t;
            if (e < E) {
                int d = dst[e];
                int b = d >> BSHIFT;
                int pos = atomicAdd(&lcnt[b], 1);
                lpacked[pos] = (unsigned int)src[e] | ((unsigned int)(d & (BSIZE - 1)) << PACK_SHIFT);
                lbslot[pos] = (unsigned char)b;
            }
        }
        __syncthreads();

#pragma unroll
        for (int j = 0; j < ECHUNK / 256; j++) {
            int s = j * 256 + t;
            if (s < cnt) {
                int b = lbslot[s];
                int pos = lbase[b] + (s - lexc[b]);
                if (pos < (b + 1) * CAP)        // overflow guard
                    packed_out[pos] = lpacked[s];
            }
        }
    }
}

// ---- prepB: bfinal (per-bucket CSR finalize) || gemm1 rows >= RA ----------
// 1024 threads. bfinal role = R7-exact logic with carved LDS; gemm role =
// 16 waves x 16 rows (256 rows/block), acc[8] (~60 VGPR so bfinal occupancy
// stays wave-capped at 2 blocks/CU as standalone).

__launch_bounds__(1024) __global__
void prepB_kernel(const unsigned int* __restrict__ packed, const int* __restrict__ ecnt,
                  int* __restrict__ rowptr, float* __restrict__ dinv,
                  int* __restrict__ ssrc,
                  const float* __restrict__ X, const float* __restrict__ W,
                  _Float16* __restrict__ outh, int RA,
                  int N, int E, int NB, int GB2) {
    __shared__ __align__(16) char shbuf[34816];

    const int t = threadIdx.x;
    const int tm = 2 * min(NB, GB2);
    bool isf;
    int bid;
    if ((int)blockIdx.x < tm) {
        isf = !(blockIdx.x & 1);
        bid = blockIdx.x >> 1;
    } else {
        bid = (tm >> 1) + ((int)blockIdx.x - tm);
        isf = (NB > GB2);
    }

    if (isf) {
        // ---------------- bfinal role ----------------------------------------
        int* ncnt = (int*)shbuf;          // [512]
        int* sbuf = ncnt + BSIZE;         // [512]
        int* bsc = sbuf + BSIZE;          // [256]
        int* bbase_sh = bsc + 256;        // [1]

        const int b = bid;

        if (t < 256) bsc[t] = (t < NB) ? min(ecnt[t], CAP) : 0;
        if (t < BSIZE) ncnt[t] = 0;
        __syncthreads();

        const int cnt = min(ecnt[b], CAP);
        const unsigned int* pb = packed + (size_t)b * CAP;
        unsigned int held[CAP / 1024];
#pragma unroll
        for (int j = 0; j < CAP / 1024; j++) {
            int e = t + j * 1024;
            if (e < cnt) {
                unsigned int p = pb[e];
                held[j] = p;
                atomicAdd(&ncnt[p >> PACK_SHIFT], 1);
            }
        }

        // bucket-base: inclusive scan of bsc (threads 0..255)
        __syncthreads();
        for (int off = 1; off < 256; off <<= 1) {
            int x = 0;
            if (t < 256 && t >= off) x = bsc[t - off];
            __syncthreads();
            if (t < 256 && t >= off) bsc[t] += x;
            __syncthreads();
        }
        if (t == 0) *bbase_sh = (b == 0) ? 0 : bsc[b - 1];

        // node-degree exclusive scan (512 entries)
        int mycnt = 0;
        if (t < BSIZE) {
            mycnt = ncnt[t];
            sbuf[t] = mycnt;
        }
        __syncthreads();
        for (int off = 1; off < BSIZE; off <<= 1) {
            int x = 0;
            if (t < BSIZE && t >= off) x = sbuf[t - off];
            __syncthreads();
            if (t < BSIZE && t >= off) sbuf[t] += x;
            __syncthreads();
        }

        const int gb = *bbase_sh;
        if (t < BSIZE) {
            int exc = (t == 0) ? 0 : sbuf[t - 1];
            int node = (b << BSHIFT) + t;
            if (node < N) {
                rowptr[node] = gb + exc;
                dinv[node] = rsqrtf((float)(mycnt + 1));  // +1 self loop
            }
            ncnt[t] = gb + exc;                 // placement cursor
        }
        if (t == 0 && b == NB - 1) rowptr[N] = gb + cnt;
        __syncthreads();

#pragma unroll
        for (int j = 0; j < CAP / 1024; j++) {
            int e = t + j * 1024;
            if (e < cnt) {
                unsigned int p = held[j];
                int d = p >> PACK_SHIFT;
                int pos = atomicAdd(&ncnt[d], 1);
                ssrc[pos] = (int)(p & PACK_MASK);
            }
        }
    } else {
        // ---------------- gemm1 role: 256 rows (16 waves x 16 rows) ----------
        constexpr int K = KDIM;       // 128
        constexpr int KS = K + 8;     // 136
        constexpr int DOUT = 128;
        constexpr int NT = DOUT / 16; // 8
        _Float16* Wl = (_Float16*)shbuf;   // 128*136*2 = 34816 B exact

        const int wave = t >> 6;      // 0..15
        const int lane = t & 63;
        const int l15 = lane & 15;
        const int quad = lane >> 4;

#pragma unroll
        for (int i = t; i < DOUT * (K / 4); i += 1024) {
            int n = i & (DOUT - 1);
            int kg = i >> 7;          // 0..31
            union { _Float16 h[4]; uint2 u; } tmp;
#pragma unroll
            for (int j = 0; j < 4; j++)
                tmp.h[j] = (_Float16)W[(size_t)(kg * 4 + j) * DOUT + n];
            *(uint2*)(&Wl[n * KS + kg * 4]) = tmp.u;
        }
        __syncthreads();

        const int rowbase = RA + bid * 256;
        const int row0 = rowbase + wave * 16 + l15;
        const int rc0 = min(row0, N - 1);

        f4v acc[NT];
#pragma unroll
        for (int ct = 0; ct < NT; ct++) acc[ct] = (f4v)0.0f;

#pragma unroll
        for (int kc = 0; kc < K; kc += 32) {
            const int kof = kc + quad * 8;
            const float* p0 = X + (size_t)rc0 * K + kof;
            h8 a0 = pack8(*(const float4*)p0, *(const float4*)(p0 + 4));
#pragma unroll
            for (int ct = 0; ct < NT; ct++) {
                h8 b = *(const h8*)(&Wl[(size_t)(ct * 16 + l15) * KS + kof]);
                acc[ct] = __builtin_amdgcn_mfma_f32_16x16x32_f16(a0, b, acc[ct], 0, 0, 0);
            }
        }

        const int rb = rowbase + wave * 16 + quad * 4;
#pragma unroll
        for (int g = 0; g < 4; g++) {
            int row = rb + g;
            if (row < N) {
                _Float16* op = outh + (size_t)row * DOUT + l15;
#pragma unroll
                for (int ct = 0; ct < NT; ct++)
                    op[ct * 16] = (_Float16)acc[ct][g];   // unscaled
            }
        }
    }
}

// ---- FUSED layer-1 aggregation + layer-2 GEMM (barrier-free GEMM) ---------
// hs1 UNSCALED; dinv applied at gather (fmac); self = di^2*h_i via acc-init.
// ssrc via dwordx4 (aligned main loop). R2 LDS layout (KS=136 pad).

__launch_bounds__(512, 8) __global__
void agg_gemm_kernel(const __half* __restrict__ hs, const int* __restrict__ rowptr,
                     const int* __restrict__ ssrc, const float* __restrict__ dinv,
                     const float* __restrict__ bias, const float* __restrict__ W2,
                     _Float16* __restrict__ hs2, int N) {
    constexpr int K = KDIM;       // 128
    constexpr int KS = K + 8;     // 136-half pad stride
    constexpr int DO2 = 64;
    __shared__ _Float16 W2l[DO2 * KS];      // 17.4 KB
    __shared__ _Float16 o_lds[8][4 * KS];   //  8.7 KB

    const int t = threadIdx.x;

#pragma unroll
    for (int i = t; i < DO2 * (K / 4); i += 512) {
        int n = i & (DO2 - 1);
        int kg = i >> 6;
        union { _Float16 h[4]; uint2 u; } tmp;
#pragma unroll
        for (int j = 0; j < 4; j++)
            tmp.h[j] = (_Float16)W2[(size_t)(kg * 4 + j) * DO2 + n];
        *(uint2*)(&W2l[n * KS + kg * 4]) = tmp.u;
    }
    __syncthreads();               // ONLY block barrier: pre-gather

    const int nl = t >> 4;
    const int node = blockIdx.x * 32 + nl;
    const int flane = t & 15;
    const int c0 = flane * 8;

    h8 oh;
    if (node < N) {
        const float di = dinv[node];
        float acc[8];
        {
            uint4 u = *(const uint4*)(hs + (size_t)node * K + c0);  // self loop
            const __half2* hp = (const __half2*)&u;
#pragma unroll
            for (int q = 0; q < 4; q++) {
                float2 f = __half22float2(hp[q]);
                acc[2 * q]     = di * f.x;
                acc[2 * q + 1] = di * f.y;
            }
        }

        const int e0 = rowptr[node];
        const int e1 = rowptr[node + 1];
        int e = e0;
        const int ealign = min(e1, (e0 + 3) & ~3);
        for (; e < ealign; e++) {
            int s = ssrc[e];
            float ds = dinv[s];
            uint4 u = *(const uint4*)(hs + (size_t)s * K + c0);
            const __half2* hp = (const __half2*)&u;
#pragma unroll
            for (int q = 0; q < 4; q++) {
                float2 f = __half22float2(hp[q]);
                acc[2 * q]     += ds * f.x;
                acc[2 * q + 1] += ds * f.y;
            }
        }
        for (; e + 4 <= e1; e += 4) {
            int4v sv = *(const int4v*)(ssrc + e);   // 16B-aligned (e%4==0)
            int s0 = sv[0], s1 = sv[1], s2 = sv[2], s3 = sv[3];
            float d0 = dinv[s0];
            float d1 = dinv[s1];
            float d2 = dinv[s2];
            float d3 = dinv[s3];
            uint4 u0 = *(const uint4*)(hs + (size_t)s0 * K + c0);
            uint4 u1 = *(const uint4*)(hs + (size_t)s1 * K + c0);
            uint4 u2 = *(const uint4*)(hs + (size_t)s2 * K + c0);
            uint4 u3 = *(const uint4*)(hs + (size_t)s3 * K + c0);
            const __half2* p0 = (const __half2*)&u0;
            const __half2* p1 = (const __half2*)&u1;
            const __half2* p2 = (const __half2*)&u2;
            const __half2* p3 = (const __half2*)&u3;
#pragma unroll
            for (int q = 0; q < 4; q++) {
                float2 f0 = __half22float2(p0[q]);
                float2 f1 = __half22float2(p1[q]);
                float2 f2 = __half22float2(p2[q]);
                float2 f3 = __half22float2(p3[q]);
                acc[2 * q]     += d0 * f0.x + d1 * f1.x + d2 * f2.x + d3 * f3.x;
                acc[2 * q + 1] += d0 * f0.y + d1 * f1.y + d2 * f2.y + d3 * f3.y;
            }
        }
        for (; e < e1; e++) {
            int s = ssrc[e];
            float ds = dinv[s];
            uint4 u = *(const uint4*)(hs + (size_t)s * K + c0);
            const __half2* hp = (const __half2*)&u;
#pragma unroll
            for (int q = 0; q < 4; q++) {
                float2 f = __half22float2(hp[q]);
                acc[2 * q]     += ds * f.x;
                acc[2 * q + 1] += ds * f.y;
            }
        }

#pragma unroll
        for (int q = 0; q < 2; q++) {
            float4 bq = *(const float4*)(bias + c0 + 4 * q);
            oh[4 * q + 0] = (_Float16)fmaxf(di * acc[4 * q + 0] + bq.x, 0.f);
            oh[4 * q + 1] = (_Float16)fmaxf(di * acc[4 * q + 1] + bq.y, 0.f);
            oh[4 * q + 2] = (_Float16)fmaxf(di * acc[4 * q + 2] + bq.z, 0.f);
            oh[4 * q + 3] = (_Float16)fmaxf(di * acc[4 * q + 3] + bq.w, 0.f);
        }
    } else {
#pragma unroll
        for (int j = 0; j < 8; j++) oh[j] = (_Float16)0.f;
    }

    // ---- phase 2: wave-local transpose + 16x64x128 MFMA (no block barrier)
    const int wv = t >> 6;
    const int a = (t >> 4) & 3;
    *(h8*)(&o_lds[wv][a * KS + c0]) = oh;
    asm volatile("s_waitcnt lgkmcnt(0)" ::: "memory");
    __builtin_amdgcn_sched_barrier(0);

    const int lane = t & 63;
    const int l15 = lane & 15;
    const int quad = lane >> 4;

    f4v acc2[4];
#pragma unroll
    for (int ct = 0; ct < 4; ct++) acc2[ct] = (f4v)0.0f;

#pragma unroll
    for (int kc = 0; kc < K; kc += 32) {
        const int kof = kc + quad * 8;
        h8 afr = *(const h8*)(&o_lds[wv][(l15 & 3) * KS + kof]);
#pragma unroll
        for (int ct = 0; ct < 4; ct++) {
            h8 b = *(const h8*)(&W2l[(size_t)(ct * 16 + l15) * KS + kof]);
            acc2[ct] = __builtin_amdgcn_mfma_f32_16x16x32_f16(afr, b, acc2[ct], 0, 0, 0);
        }
    }

    f4v av = (quad == 0) ? acc2[0] : (quad == 1) ? acc2[1]
           : (quad == 2) ? acc2[2] : acc2[3];
    const int rowbase = blockIdx.x * 32 + wv * 4;
#pragma unroll
    for (int g = 0; g < 4; g++) {
        int r = rowbase + g;
        if (r < N)
            hs2[(size_t)r * DO2 + quad * 16 + l15] = (_Float16)(av[g] * dinv[r]);
    }
}

// ---- Aggregation: out[i] = dinv[i]*(sum_e hs[src[e]] + hs[i]) + b ---------
// hs fp16 (pre-scaled by source dinv); ssrc dwordx4 main loop.

template <int DOUT, bool RELU, bool HOUT>
__launch_bounds__(256) __global__
void agg_kernel(const __half* __restrict__ hs, const int* __restrict__ rowptr,
                const int* __restrict__ ssrc, const float* __restrict__ dinv,
                const float* __restrict__ bias, void* __restrict__ outv, int N) {
    constexpr int TPN = DOUT / 8;
    const int npb = blockDim.x / TPN;
    const int node = blockIdx.x * npb + threadIdx.x / TPN;
    if (node >= N) return;
    const int lane = threadIdx.x % TPN;
    const int c0 = lane * 8;

    float acc[8];
    {
        uint4 u = *(const uint4*)(hs + (size_t)node * DOUT + c0);  // self loop
        const __half2* hp = (const __half2*)&u;
#pragma unroll
        for (int q = 0; q < 4; q++) {
            float2 f = __half22float2(hp[q]);
            acc[2 * q] = f.x;
            acc[2 * q + 1] = f.y;
        }
    }

    const int e0 = rowptr[node];
    const int e1 = rowptr[node + 1];
    int e = e0;
    const int ealign = min(e1, (e0 + 3) & ~3);
    for (; e < ealign; e++) {
        int s = ssrc[e];
        uint4 u = *(const uint4*)(hs + (size_t)s * DOUT + c0);
        const __half2* hp = (const __half2*)&u;
#pragma unroll
        for (int q = 0; q < 4; q++) {
            float2 f = __half22float2(hp[q]);
            acc[2 * q] += f.x;
            acc[2 * q + 1] += f.y;
        }
    }
    for (; e + 4 <= e1; e += 4) {
        int4v sv = *(const int4v*)(ssrc + e);   // 16B-aligned (e%4==0)
        int s0 = sv[0], s1 = sv[1], s2 = sv[2], s3 = sv[3];
        uint4 u0 = *(const uint4*)(hs + (size_t)s0 * DOUT + c0);
        uint4 u1 = *(const uint4*)(hs + (size_t)s1 * DOUT + c0);
        uint4 u2 = *(const uint4*)(hs + (size_t)s2 * DOUT + c0);
        uint4 u3 = *(const uint4*)(hs + (size_t)s3 * DOUT + c0);
        const __half2* p0 = (const __half2*)&u0;
        const __half2* p1 = (const __half2*)&u1;
        const __half2* p2 = (const __half2*)&u2;
        const __half2* p3 = (const __half2*)&u3;
#pragma unroll
        for (int q = 0; q < 4; q++) {
            float2 f0 = __half22float2(p0[q]);
            float2 f1 = __half22float2(p1[q]);
            float2 f2 = __half22float2(p2[q]);
            float2 f3 = __half22float2(p3[q]);
            acc[2 * q]     += (f0.x + f1.x) + (f2.x + f3.x);
            acc[2 * q + 1] += (f0.y + f1.y) + (f2.y + f3.y);
        }
    }
    for (; e < e1; e++) {
        int s = ssrc[e];
        uint4 u = *(const uint4*)(hs + (size_t)s * DOUT + c0);
        const __half2* hp = (const __half2*)&u;
#pragma unroll
        for (int q = 0; q < 4; q++) {
            float2 f = __half22float2(hp[q]);
            acc[2 * q] += f.x;
            acc[2 * q + 1] += f.y;
        }
    }

    const float di = dinv[node];
    float o[8];
#pragma unroll
    for (int q = 0; q < 2; q++) {
        float4 bq = *(const float4*)(bias + c0 + 4 * q);
        o[4 * q + 0] = di * acc[4 * q + 0] + bq.x;
        o[4 * q + 1] = di * acc[4 * q + 1] + bq.y;
        o[4 * q + 2] = di * acc[4 * q + 2] + bq.z;
        o[4 * q + 3] = di * acc[4 * q + 3] + bq.w;
    }
    if (RELU) {
#pragma unroll
        for (int j = 0; j < 8; j++) o[j] = fmaxf(o[j], 0.f);
    }
    if (HOUT) {
        union { __half2 h[4]; uint4 u; } pk;
#pragma unroll
        for (int q = 0; q < 4; q++)
            pk.h[q] = __floats2half2_rn(o[2 * q], o[2 * q + 1]);
        *(uint4*)((__half*)outv + (size_t)node * DOUT + c0) = pk.u;
    } else {
        float* op = (float*)outv + (size_t)node * DOUT + c0;
        *(float4*)op = make_float4(o[0], o[1], o[2], o[3]);
        *(float4*)(op + 4) = make_float4(o[4], o[5], o[6], o[7]);
    }
}

// ---------------------------------------------------------------------------

extern "C" void kernel_launch(void* const* d_in, const int* in_sizes, int n_in,
                              void* d_out, int out_size, void* d_ws, size_t ws_size,
                              hipStream_t stream) {
    const float* x  = (const float*)d_in[0];
    const int*   ei = (const int*)d_in[1];
    const float* W1 = (const float*)d_in[3];
    const float* b1 = (const float*)d_in[4];
    const float* W2 = (const float*)d_in[5];
    const float* b2 = (const float*)d_in[6];
    float* out = (float*)d_out;

    const int N = in_sizes[0] / KDIM;  // 100000
    const int E = in_sizes[1] / 2;     // 1600000
    const int* esrc = ei;
    const int* edst = ei + E;
    const int NB = (N + BSIZE - 1) >> BSHIFT;  // 196

    char* ws = (char*)d_ws;
    size_t off = 0;
    auto alloc = [&](size_t bytes) {
        size_t p = off;
        off = (off + bytes + 511) & ~(size_t)511;
        return p;
    };
    int*      ecnt    = (int*)(ws + alloc((size_t)NB * 4));
    int*      rowptr  = (int*)(ws + alloc((size_t)(N + 1) * 4));
    float*    dinv    = (float*)(ws + alloc((size_t)N * 4));
    int*      ssrc    = (int*)(ws + alloc((size_t)E * 4));
    _Float16* hs1     = (_Float16*)(ws + alloc((size_t)N * KDIM * 2));  // fp16 layer-1 pre-agg
    _Float16* hs2     = (_Float16*)(ws + alloc((size_t)N * 64 * 2));    // fp16 layer-2 pre-agg
    // packed aliases hs2 (8.0MB <= 12.8MB): written by prepA bscatter role,
    // consumed by prepB bfinal role, then hs2 overwritten by agg_gemm.
    unsigned int* packed = (unsigned int*)hs2;
    (void)ws_size; (void)n_in; (void)out_size;

    const int eb = (E + ECHUNK - 1) / ECHUNK;      // 782
    const int gbA = (N / 2) / 128;                 // 390 -> rows [0, 49920)
    const int RA = gbA * 128;                      // 49920
    const int gbB = (N - RA + 255) / 256;          // 196 -> rows [RA, N)

    hipMemsetAsync(ecnt, 0, (size_t)NB * 4, stream);

    // prepA: gemm1 first half || bscatter
    prepA_kernel<<<gbA + eb, 256, 0, stream>>>(x, W1, hs1, esrc, edst, ecnt,
                                               packed, N, E, NB, gbA, eb);
    // prepB: bfinal || gemm1 second half
    prepB_kernel<<<NB + gbB, 1024, 0, stream>>>(packed, ecnt, rowptr, dinv, ssrc,
                                                x, W1, hs1, RA, N, E, NB, gbB);

    // FUSED: agg1 (relu, dinv at gather) + per-wave gemm2 -> hs2
    agg_gemm_kernel<<<(N + 31) / 32, 512, 0, stream>>>(
        (const __half*)hs1, rowptr, ssrc, dinv, b1, W2, hs2, N);

    // layer 2 aggregation: out = dinv*(gather+self) + b2
    agg_kernel<64, false, false><<<(N + 31) / 32, 256, 0, stream>>>(
        (const __half*)hs2, rowptr, ssrc, dinv, b2, out, N);
}

// Round 9
// 245.930 us; speedup vs baseline: 1.0360x; 1.0360x over previous
//
#include <hip/hip_runtime.h>
#include <hip/hip_fp16.h>

// ---------------------------------------------------------------------------
// GCN 2-layer forward on MI355X.  (R9 = exact revert to R7 best, 246.3 us.)
//   prep (MERGED): gemm1-role blocks compute hs1 = fp16(X @ W1) (UNSCALED --
//     dinv dependency removed) CONCURRENTLY with bscatter-role blocks
//     radix-partitioning edges. packed aliases hs2 (consumed by bfinal before
//     agg_gemm writes hs2), so roles never share a buffer.
//   bfinal: one 1024-thr block per bucket -> rowptr/dinv/ssrc. Standalone:
//     R8 measured that merging a gemm1-half into bfinal's kernel REGRESSED
//     ~6us (merged VGPR=max(roles) > 64 halves 1024-thr co-residency).
//   FUSED agg1+gemm2 (R2 layout, KS=136 pad -- R6 proved swizzle slower):
//     - dinv applied AT GATHER (fmac, +2.3us vs pre-scaled hs1 -- the price
//       of overlapping gemm1 with bscatter, net win ~7us).
//     - ssrc SCALAR loads (R8 measured dwordx4 +2.3us: ssrc loads are
//       same-address broadcasts within a node group, already cheap; the
//       dwordx4 alignment prologue added divergence).
//     - per-wave 16x64x128 MFMA, wave-local LDS + lgkmcnt(0), no block
//       barrier after gather. __launch_bounds__(512,8) (R5: (512,4) PINS
//       occupancy at 4 waves/EU -> 70%->36%).
//   agg2: out = dinv*(gather+self)+b2 (R2-exact).
//   Gather kernels sit at the random-gather L2-miss-path ceiling
//   (~3.0-3.6 TB/s; FETCH = 8 XCDs x table = structural floor).
// ---------------------------------------------------------------------------

#define KDIM 128
#define BSHIFT 9
#define BSIZE 512
#define ECHUNK 2048
#define CAP 10240              // per-bucket capacity; mean 8192, sigma~90 -> 22σ
#define PACK_SHIFT 20
#define PACK_MASK ((1u << PACK_SHIFT) - 1)

typedef _Float16 h8 __attribute__((ext_vector_type(8)));
typedef float f4v __attribute__((ext_vector_type(4)));

__device__ inline h8 pack8(float4 u, float4 v) {
    h8 r;
    r[0] = (_Float16)u.x; r[1] = (_Float16)u.y; r[2] = (_Float16)u.z; r[3] = (_Float16)u.w;
    r[4] = (_Float16)v.x; r[5] = (_Float16)v.y; r[6] = (_Float16)v.z; r[7] = (_Float16)v.w;
    return r;
}

// ---- MERGED prep: gemm1 (hs1 = fp16(X @ W1), unscaled) || bscatter --------
// Role by blockIdx parity (interleaved so both co-resident); shared LDS
// buffer sized for the larger role (gemm1: 128*136*2 = 34816 B).

__launch_bounds__(256) __global__
void prep_kernel(const float* __restrict__ X, const float* __restrict__ W,
                 _Float16* __restrict__ outh,
                 const int* __restrict__ src, const int* __restrict__ dst,
                 int* __restrict__ ecnt, unsigned int* __restrict__ packed_out,
                 int N, int E, int NB, int GB, int EB) {
    __shared__ __align__(16) char shbuf[34816];

    const int t = threadIdx.x;
    const int tm = 2 * min(GB, EB);
    bool isg;
    int bid;
    if ((int)blockIdx.x < tm) {
        isg = !(blockIdx.x & 1);
        bid = blockIdx.x >> 1;
    } else {
        bid = (tm >> 1) + ((int)blockIdx.x - tm);
        isg = (GB > EB);
    }

    if (isg) {
        // ---------------- gemm1 role: 128 rows x 128 cols --------------------
        constexpr int K = KDIM;       // 128
        constexpr int KS = K + 8;     // 136
        constexpr int DOUT = 128;
        constexpr int NT = DOUT / 16; // 8
        _Float16* Wl = (_Float16*)shbuf;

        const int wave = t >> 6;
        const int lane = t & 63;
        const int l15 = lane & 15;
        const int quad = lane >> 4;

        // stage W (fp32 [K][DOUT] row-major) -> Wl fp16 n-major [n][k]
#pragma unroll
        for (int i = t; i < DOUT * (K / 4); i += 256) {
            int n = i & (DOUT - 1);
            int kg = i >> 7;       // 0..31
            union { _Float16 h[4]; uint2 u; } tmp;
#pragma unroll
            for (int j = 0; j < 4; j++)
                tmp.h[j] = (_Float16)W[(size_t)(kg * 4 + j) * DOUT + n];
            *(uint2*)(&Wl[n * KS + kg * 4]) = tmp.u;
        }
        __syncthreads();

        const int rowbase = bid * 128;
        const int row0 = rowbase + wave * 32 + l15;
        const int row1 = row0 + 16;
        const int rc0 = min(row0, N - 1);   // clamp: OOB A rows feed OOB D rows
        const int rc1 = min(row1, N - 1);

        f4v acc[2][NT];
#pragma unroll
        for (int r = 0; r < 2; r++)
#pragma unroll
            for (int ct = 0; ct < NT; ct++) acc[r][ct] = (f4v)0.0f;

#pragma unroll
        for (int kc = 0; kc < K; kc += 32) {
            const int kof = kc + quad * 8;
            const float* p0 = X + (size_t)rc0 * K + kof;
            const float* p1 = X + (size_t)rc1 * K + kof;
            h8 a0 = pack8(*(const float4*)p0, *(const float4*)(p0 + 4));
            h8 a1 = pack8(*(const float4*)p1, *(const float4*)(p1 + 4));
#pragma unroll
            for (int ct = 0; ct < NT; ct++) {
                h8 b = *(const h8*)(&Wl[(size_t)(ct * 16 + l15) * KS + kof]);
                acc[0][ct] = __builtin_amdgcn_mfma_f32_16x16x32_f16(a0, b, acc[0][ct], 0, 0, 0);
                acc[1][ct] = __builtin_amdgcn_mfma_f32_16x16x32_f16(a1, b, acc[1][ct], 0, 0, 0);
            }
        }

#pragma unroll
        for (int r = 0; r < 2; r++) {
            const int rb = rowbase + wave * 32 + r * 16 + quad * 4;
#pragma unroll
            for (int g = 0; g < 4; g++) {
                int row = rb + g;
                if (row < N) {
                    _Float16* op = outh + (size_t)row * DOUT + l15;
#pragma unroll
                    for (int ct = 0; ct < NT; ct++)
                        op[ct * 16] = (_Float16)acc[r][ct][g];   // unscaled
                }
            }
        }
    } else {
        // ---------------- bscatter role: 2048-edge chunk ---------------------
        int* lcnt = (int*)shbuf;                          // [256]
        int* lexc = lcnt + 256;                           // [256]
        int* lbase = lexc + 256;                          // [256]
        unsigned int* lpacked = (unsigned int*)(lbase + 256);        // [2048]
        unsigned char* lbslot = (unsigned char*)(lpacked + ECHUNK);  // [2048]

        lcnt[t] = 0;
        __syncthreads();

        const int base = bid * ECHUNK;
        const int cnt = min(ECHUNK, E - base);

#pragma unroll
        for (int j = 0; j < ECHUNK / 256; j++) {
            int e = base + j * 256 + t;
            if (e < E) atomicAdd(&lcnt[dst[e] >> BSHIFT], 1);
        }
        __syncthreads();

        lexc[t] = lcnt[t];
        __syncthreads();
        for (int off = 1; off < 256; off <<= 1) {
            int x = (t >= off) ? lexc[t - off] : 0;
            __syncthreads();
            if (t >= off) lexc[t] += x;
            __syncthreads();
        }
        lexc[t] = lexc[t] - lcnt[t];            // own slot only: safe

        if (t < NB && lcnt[t]) lbase[t] = t * CAP + atomicAdd(&ecnt[t], lcnt[t]);
        __syncthreads();
        lcnt[t] = lexc[t];                      // local placement cursor
        __syncthreads();

#pragma unroll
        for (int j = 0; j < ECHUNK / 256; j++) {
            int e = base + j * 256 + t;
            if (e < E) {
                int d = dst[e];
                int b = d >> BSHIFT;
                int pos = atomicAdd(&lcnt[b], 1);
                lpacked[pos] = (unsigned int)src[e] | ((unsigned int)(d & (BSIZE - 1)) << PACK_SHIFT);
                lbslot[pos] = (unsigned char)b;
            }
        }
        __syncthreads();

#pragma unroll
        for (int j = 0; j < ECHUNK / 256; j++) {
            int s = j * 256 + t;
            if (s < cnt) {
                int b = lbslot[s];
                int pos = lbase[b] + (s - lexc[b]);
                if (pos < (b + 1) * CAP)        // overflow guard
                    packed_out[pos] = lpacked[s];
            }
        }
    }
}

// ---- per-bucket: bucket-base scan + degree count + node scan + place ------

__launch_bounds__(1024) __global__
void bfinal_kernel(const unsigned int* __restrict__ packed, const int* __restrict__ ecnt,
                   int* __restrict__ rowptr, float* __restrict__ dinv,
                   int* __restrict__ ssrc, int N, int E, int NB) {
    __shared__ int ncnt[BSIZE];
    __shared__ int sbuf[BSIZE];
    __shared__ int bsc[256];
    __shared__ int bbase_sh;

    const int t = threadIdx.x;
    const int b = blockIdx.x;

    if (t < 256) bsc[t] = (t < NB) ? min(ecnt[t], CAP) : 0;
    if (t < BSIZE) ncnt[t] = 0;
    __syncthreads();

    // load this bucket's packed run into registers + count node degrees
    const int cnt = min(ecnt[b], CAP);
    const unsigned int* pb = packed + (size_t)b * CAP;
    unsigned int held[CAP / 1024];
#pragma unroll
    for (int j = 0; j < CAP / 1024; j++) {
        int e = t + j * 1024;
        if (e < cnt) {
            unsigned int p = pb[e];
            held[j] = p;
            atomicAdd(&ncnt[p >> PACK_SHIFT], 1);
        }
    }

    // bucket-base: inclusive scan of bsc (threads 0..255)
    __syncthreads();
    for (int off = 1; off < 256; off <<= 1) {
        int x = 0;
        if (t < 256 && t >= off) x = bsc[t - off];
        __syncthreads();
        if (t < 256 && t >= off) bsc[t] += x;
        __syncthreads();
    }
    if (t == 0) bbase_sh = (b == 0) ? 0 : bsc[b - 1];

    // node-degree exclusive scan (512 entries, threads 0..511)
    int mycnt = 0;
    if (t < BSIZE) {
        mycnt = ncnt[t];
        sbuf[t] = mycnt;
    }
    __syncthreads();
    for (int off = 1; off < BSIZE; off <<= 1) {
        int x = 0;
        if (t < BSIZE && t >= off) x = sbuf[t - off];
        __syncthreads();
        if (t < BSIZE && t >= off) sbuf[t] += x;
        __syncthreads();
    }

    const int gb = bbase_sh;
    if (t < BSIZE) {
        int exc = (t == 0) ? 0 : sbuf[t - 1];
        int node = (b << BSHIFT) + t;
        if (node < N) {
            rowptr[node] = gb + exc;
            dinv[node] = rsqrtf((float)(mycnt + 1));  // +1 self loop
        }
        ncnt[t] = gb + exc;                 // becomes placement cursor
    }
    if (t == 0 && b == NB - 1) rowptr[N] = gb + cnt;
    __syncthreads();

    // placement from registers; ssrc window ~33 KB -> L2-resident
#pragma unroll
    for (int j = 0; j < CAP / 1024; j++) {
        int e = t + j * 1024;
        if (e < cnt) {
            unsigned int p = held[j];
            int d = p >> PACK_SHIFT;
            int pos = atomicAdd(&ncnt[d], 1);
            ssrc[pos] = (int)(p & PACK_MASK);
        }
    }
}

// ---- FUSED layer-1 aggregation + layer-2 GEMM (barrier-free GEMM) ---------
// hs1 is UNSCALED; source scaling applied at gather via fmac (same inst
// count); self-loop = di^2 * h_i via acc-init. R2-proven LDS layout
// (KS=136 pad, no swizzle). ssrc scalar loads (R8: dwordx4 regressed).

__launch_bounds__(512, 8) __global__
void agg_gemm_kernel(const __half* __restrict__ hs, const int* __restrict__ rowptr,
                     const int* __restrict__ ssrc, const float* __restrict__ dinv,
                     const float* __restrict__ bias, const float* __restrict__ W2,
                     _Float16* __restrict__ hs2, int N) {
    constexpr int K = KDIM;       // 128 (layer-1 width = GEMM K)
    constexpr int KS = K + 8;     // 136-half pad stride (16B aligned)
    constexpr int DO2 = 64;       // layer-2 width
    __shared__ _Float16 W2l[DO2 * KS];      // 17.4 KB, n-major fp16
    __shared__ _Float16 o_lds[8][4 * KS];   //  8.7 KB, 4 rows per wave

    const int t = threadIdx.x;

    // stage W2 (fp32 [128][64] row-major) -> fp16 n-major [n][k]
#pragma unroll
    for (int i = t; i < DO2 * (K / 4); i += 512) {
        int n = i & (DO2 - 1);
        int kg = i >> 6;           // 0..31
        union { _Float16 h[4]; uint2 u; } tmp;
#pragma unroll
        for (int j = 0; j < 4; j++)
            tmp.h[j] = (_Float16)W2[(size_t)(kg * 4 + j) * DO2 + n];
        *(uint2*)(&W2l[n * KS + kg * 4]) = tmp.u;
    }
    __syncthreads();               // ONLY block barrier: uniform cost, pre-gather

    // ---- phase 1: gather-aggregate (16 lanes/node, 4 nodes/wave) ----------
    const int nl = t >> 4;                 // node slot 0..31
    const int node = blockIdx.x * 32 + nl;
    const int flane = t & 15;
    const int c0 = flane * 8;

    h8 oh;
    if (node < N) {
        const float di = dinv[node];
        float acc[8];
        {
            uint4 u = *(const uint4*)(hs + (size_t)node * K + c0);  // self loop
            const __half2* hp = (const __half2*)&u;
#pragma unroll
            for (int q = 0; q < 4; q++) {
                float2 f = __half22float2(hp[q]);
                acc[2 * q]     = di * f.x;          // self: di^2*h_i after final *di
                acc[2 * q + 1] = di * f.y;
            }
        }

        const int e0 = rowptr[node];
        const int e1 = rowptr[node + 1];
        int e = e0;
        for (; e + 4 <= e1; e += 4) {
            int s0 = ssrc[e + 0];
            int s1 = ssrc[e + 1];
            int s2 = ssrc[e + 2];
            int s3 = ssrc[e + 3];
            float d0 = dinv[s0];
            float d1 = dinv[s1];
            float d2 = dinv[s2];
            float d3 = dinv[s3];
            uint4 u0 = *(const uint4*)(hs + (size_t)s0 * K + c0);
            uint4 u1 = *(const uint4*)(hs + (size_t)s1 * K + c0);
            uint4 u2 = *(const uint4*)(hs + (size_t)s2 * K + c0);
            uint4 u3 = *(const uint4*)(hs + (size_t)s3 * K + c0);
            const __half2* p0 = (const __half2*)&u0;
            const __half2* p1 = (const __half2*)&u1;
            const __half2* p2 = (const __half2*)&u2;
            const __half2* p3 = (const __half2*)&u3;
#pragma unroll
            for (int q = 0; q < 4; q++) {
                float2 f0 = __half22float2(p0[q]);
                float2 f1 = __half22float2(p1[q]);
                float2 f2 = __half22float2(p2[q]);
                float2 f3 = __half22float2(p3[q]);
                acc[2 * q]     += d0 * f0.x + d1 * f1.x + d2 * f2.x + d3 * f3.x;
                acc[2 * q + 1] += d0 * f0.y + d1 * f1.y + d2 * f2.y + d3 * f3.y;
            }
        }
        for (; e < e1; e++) {
            int s = ssrc[e];
            float ds = dinv[s];
            uint4 u = *(const uint4*)(hs + (size_t)s * K + c0);
            const __half2* hp = (const __half2*)&u;
#pragma unroll
            for (int q = 0; q < 4; q++) {
                float2 f = __half22float2(hp[q]);
                acc[2 * q]     += ds * f.x;
                acc[2 * q + 1] += ds * f.y;
            }
        }

#pragma unroll
        for (int q = 0; q < 2; q++) {
            float4 bq = *(const float4*)(bias + c0 + 4 * q);
            oh[4 * q + 0] = (_Float16)fmaxf(di * acc[4 * q + 0] + bq.x, 0.f);
            oh[4 * q + 1] = (_Float16)fmaxf(di * acc[4 * q + 1] + bq.y, 0.f);
            oh[4 * q + 2] = (_Float16)fmaxf(di * acc[4 * q + 2] + bq.z, 0.f);
            oh[4 * q + 3] = (_Float16)fmaxf(di * acc[4 * q + 3] + bq.w, 0.f);
        }
    } else {
#pragma unroll
        for (int j = 0; j < 8; j++) oh[j] = (_Float16)0.f;
    }

    // ---- phase 2: wave-local transpose + 16x64x128 MFMA (no block barrier)
    const int wv = t >> 6;
    const int a = (t >> 4) & 3;            // node slot within wave (row 0..3)
    *(h8*)(&o_lds[wv][a * KS + c0]) = oh;
    asm volatile("s_waitcnt lgkmcnt(0)" ::: "memory");   // wave-local ordering
    __builtin_amdgcn_sched_barrier(0);

    const int lane = t & 63;
    const int l15 = lane & 15;
    const int quad = lane >> 4;

    f4v acc2[4];
#pragma unroll
    for (int ct = 0; ct < 4; ct++) acc2[ct] = (f4v)0.0f;

#pragma unroll
    for (int kc = 0; kc < K; kc += 32) {
        const int kof = kc + quad * 8;
        // A rows 4-15 duplicate rows 0-3 -> duplicate D rows, discarded
        h8 afr = *(const h8*)(&o_lds[wv][(l15 & 3) * KS + kof]);
#pragma unroll
        for (int ct = 0; ct < 4; ct++) {
            h8 b = *(const h8*)(&W2l[(size_t)(ct * 16 + l15) * KS + kof]);
            acc2[ct] = __builtin_amdgcn_mfma_f32_16x16x32_f16(afr, b, acc2[ct], 0, 0, 0);
        }
    }

    // quad q holds rows q*4+g = node (g) content (dup rows) -> write tile q.
    f4v av = (quad == 0) ? acc2[0] : (quad == 1) ? acc2[1]
           : (quad == 2) ? acc2[2] : acc2[3];
    const int rowbase = blockIdx.x * 32 + wv * 4;
#pragma unroll
    for (int g = 0; g < 4; g++) {
        int r = rowbase + g;
        if (r < N)
            hs2[(size_t)r * DO2 + quad * 16 + l15] = (_Float16)(av[g] * dinv[r]);
    }
}

// ---- Aggregation: out[i] = act(dinv[i]*(sum_e hs[src[e]] + hs[i]) + b) ----
// hs fp16 (pre-scaled by source dinv); TPN = DOUT/8 lanes/node; unroll-4.

template <int DOUT, bool RELU, bool HOUT>
__launch_bounds__(256) __global__
void agg_kernel(const __half* __restrict__ hs, const int* __restrict__ rowptr,
                const int* __restrict__ ssrc, const float* __restrict__ dinv,
                const float* __restrict__ bias, void* __restrict__ outv, int N) {
    constexpr int TPN = DOUT / 8;
    const int npb = blockDim.x / TPN;
    const int node = blockIdx.x * npb + threadIdx.x / TPN;
    if (node >= N) return;
    const int lane = threadIdx.x % TPN;
    const int c0 = lane * 8;

    float acc[8];
    {
        uint4 u = *(const uint4*)(hs + (size_t)node * DOUT + c0);  // self loop
        const __half2* hp = (const __half2*)&u;
#pragma unroll
        for (int q = 0; q < 4; q++) {
            float2 f = __half22float2(hp[q]);
            acc[2 * q] = f.x;
            acc[2 * q + 1] = f.y;
        }
    }

    const int e0 = rowptr[node];
    const int e1 = rowptr[node + 1];
    int e = e0;
    for (; e + 4 <= e1; e += 4) {
        int s0 = ssrc[e + 0];
        int s1 = ssrc[e + 1];
        int s2 = ssrc[e + 2];
        int s3 = ssrc[e + 3];
        uint4 u0 = *(const uint4*)(hs + (size_t)s0 * DOUT + c0);
        uint4 u1 = *(const uint4*)(hs + (size_t)s1 * DOUT + c0);
        uint4 u2 = *(const uint4*)(hs + (size_t)s2 * DOUT + c0);
        uint4 u3 = *(const uint4*)(hs + (size_t)s3 * DOUT + c0);
        const __half2* p0 = (const __half2*)&u0;
        const __half2* p1 = (const __half2*)&u1;
        const __half2* p2 = (const __half2*)&u2;
        const __half2* p3 = (const __half2*)&u3;
#pragma unroll
        for (int q = 0; q < 4; q++) {
            float2 f0 = __half22float2(p0[q]);
            float2 f1 = __half22float2(p1[q]);
            float2 f2 = __half22float2(p2[q]);
            float2 f3 = __half22float2(p3[q]);
            acc[2 * q]     += (f0.x + f1.x) + (f2.x + f3.x);
            acc[2 * q + 1] += (f0.y + f1.y) + (f2.y + f3.y);
        }
    }
    for (; e < e1; e++) {
        int s = ssrc[e];
        uint4 u = *(const uint4*)(hs + (size_t)s * DOUT + c0);
        const __half2* hp = (const __half2*)&u;
#pragma unroll
        for (int q = 0; q < 4; q++) {
            float2 f = __half22float2(hp[q]);
            acc[2 * q] += f.x;
            acc[2 * q + 1] += f.y;
        }
    }

    const float di = dinv[node];
    float o[8];
#pragma unroll
    for (int q = 0; q < 2; q++) {
        float4 bq = *(const float4*)(bias + c0 + 4 * q);
        o[4 * q + 0] = di * acc[4 * q + 0] + bq.x;
        o[4 * q + 1] = di * acc[4 * q + 1] + bq.y;
        o[4 * q + 2] = di * acc[4 * q + 2] + bq.z;
        o[4 * q + 3] = di * acc[4 * q + 3] + bq.w;
    }
    if (RELU) {
#pragma unroll
        for (int j = 0; j < 8; j++) o[j] = fmaxf(o[j], 0.f);
    }
    if (HOUT) {
        union { __half2 h[4]; uint4 u; } pk;
#pragma unroll
        for (int q = 0; q < 4; q++)
            pk.h[q] = __floats2half2_rn(o[2 * q], o[2 * q + 1]);
        *(uint4*)((__half*)outv + (size_t)node * DOUT + c0) = pk.u;
    } else {
        float* op = (float*)outv + (size_t)node * DOUT + c0;
        *(float4*)op = make_float4(o[0], o[1], o[2], o[3]);
        *(float4*)(op + 4) = make_float4(o[4], o[5], o[6], o[7]);
    }
}

// ---------------------------------------------------------------------------

extern "C" void kernel_launch(void* const* d_in, const int* in_sizes, int n_in,
                              void* d_out, int out_size, void* d_ws, size_t ws_size,
                              hipStream_t stream) {
    const float* x  = (const float*)d_in[0];
    const int*   ei = (const int*)d_in[1];
    const float* W1 = (const float*)d_in[3];
    const float* b1 = (const float*)d_in[4];
    const float* W2 = (const float*)d_in[5];
    const float* b2 = (const float*)d_in[6];
    float* out = (float*)d_out;

    const int N = in_sizes[0] / KDIM;  // 100000
    const int E = in_sizes[1] / 2;     // 1600000
    const int* esrc = ei;
    const int* edst = ei + E;
    const int NB = (N + BSIZE - 1) >> BSHIFT;  // 196

    char* ws = (char*)d_ws;
    size_t off = 0;
    auto alloc = [&](size_t bytes) {
        size_t p = off;
        off = (off + bytes + 511) & ~(size_t)511;
        return p;
    };
    int*      ecnt    = (int*)(ws + alloc((size_t)NB * 4));
    int*      rowptr  = (int*)(ws + alloc((size_t)(N + 1) * 4));
    float*    dinv    = (float*)(ws + alloc((size_t)N * 4));
    int*      ssrc    = (int*)(ws + alloc((size_t)E * 4));
    _Float16* hs1     = (_Float16*)(ws + alloc((size_t)N * KDIM * 2));  // fp16 layer-1 pre-agg
    _Float16* hs2     = (_Float16*)(ws + alloc((size_t)N * 64 * 2));    // fp16 layer-2 pre-agg
    // packed aliases hs2 (NB*CAP*4 = 8.0MB <= 12.8MB): written by bscatter
    // role, consumed by bfinal, then hs2 overwritten by agg_gemm. gemm1 role
    // writes hs1 concurrently -- DISJOINT from hs2.
    unsigned int* packed = (unsigned int*)hs2;
    (void)ws_size; (void)n_in; (void)out_size;

    const int eb = (E + ECHUNK - 1) / ECHUNK;   // 782
    const int gb = (N + 127) / 128;             // 782

    hipMemsetAsync(ecnt, 0, (size_t)NB * 4, stream);

    // gemm1 (hs1 = fp16(X@W1), unscaled) || bscatter -- data-independent
    prep_kernel<<<gb + eb, 256, 0, stream>>>(x, W1, hs1, esrc, edst, ecnt,
                                             packed, N, E, NB, gb, eb);
    bfinal_kernel<<<NB, 1024, 0, stream>>>(packed, ecnt, rowptr, dinv, ssrc, N, E, NB);

    // FUSED: agg1 (relu, dinv at gather) + per-wave gemm2 -> hs2
    agg_gemm_kernel<<<(N + 31) / 32, 512, 0, stream>>>(
        (const __half*)hs1, rowptr, ssrc, dinv, b1, W2, hs2, N);

    // layer 2 aggregation: out = dinv*(gather+self) + b2
    agg_kernel<64, false, false><<<(N + 31) / 32, 256, 0, stream>>>(
        (const __half*)hs2, rowptr, ssrc, dinv, b2, out, N);
}

// Round 10
// 243.758 us; speedup vs baseline: 1.0452x; 1.0089x over previous
//
#include <hip/hip_runtime.h>
#include <hip/hip_fp16.h>

// ---------------------------------------------------------------------------
// GCN 2-layer forward on MI355X.  (R10 = R9/R7 structure + wave-shuffle scans
//   in bfinal/bscatter: bfinal runs 196 blocks x 1024 thr = <1 block/CU, so
//   its ~20 Hillis-Steele barriers were fully latency-exposed; now 5.)
//   prep (MERGED): gemm1-role blocks compute hs1 = fp16(X @ W1) (UNSCALED)
//     CONCURRENTLY with bscatter-role blocks radix-partitioning edges.
//     packed aliases hs2 (consumed by bfinal before agg_gemm writes hs2).
//   bfinal: one 1024-thr block per bucket -> rowptr/dinv/ssrc. Standalone
//     (R8: merging gemm1-half regressed ~6us via VGPR=max(roles)).
//     Degree scan = per-wave __shfl_up scan + 8-entry wave-total scan;
//     bucket-base needs only ONE prefix -> masked wave REDUCE, run on idle
//     threads 512..767 concurrently with the degree scan.
//   FUSED agg1+gemm2 (R2 layout, KS=136 pad -- R6 proved swizzle slower):
//     - dinv applied AT GATHER (fmac); self = di^2*h_i via acc-init.
//     - ssrc SCALAR loads (R8: dwordx4 regressed; broadcasts already cheap).
//     - per-wave 16x64x128 MFMA, wave-local LDS + lgkmcnt(0).
//       __launch_bounds__(512,8) (R5: (512,4) PINS occupancy 70%->36%).
//   agg2: out = dinv*(gather+self)+b2 (R2-exact).
//   Gather kernels sit at the random-gather L2-miss-path ceiling
//   (~3.1-3.6 TB/s; FETCH = 8 XCDs x table = structural floor).
// ---------------------------------------------------------------------------

#define KDIM 128
#define BSHIFT 9
#define BSIZE 512
#define ECHUNK 2048
#define CAP 10240              // per-bucket capacity; mean 8192, sigma~90 -> 22σ
#define PACK_SHIFT 20
#define PACK_MASK ((1u << PACK_SHIFT) - 1)

typedef _Float16 h8 __attribute__((ext_vector_type(8)));
typedef float f4v __attribute__((ext_vector_type(4)));

__device__ inline h8 pack8(float4 u, float4 v) {
    h8 r;
    r[0] = (_Float16)u.x; r[1] = (_Float16)u.y; r[2] = (_Float16)u.z; r[3] = (_Float16)u.w;
    r[4] = (_Float16)v.x; r[5] = (_Float16)v.y; r[6] = (_Float16)v.z; r[7] = (_Float16)v.w;
    return r;
}

// ---- MERGED prep: gemm1 (hs1 = fp16(X @ W1), unscaled) || bscatter --------
// Role by blockIdx parity (interleaved so both co-resident); shared LDS
// buffer sized for the larger role (gemm1: 128*136*2 = 34816 B).

__launch_bounds__(256) __global__
void prep_kernel(const float* __restrict__ X, const float* __restrict__ W,
                 _Float16* __restrict__ outh,
                 const int* __restrict__ src, const int* __restrict__ dst,
                 int* __restrict__ ecnt, unsigned int* __restrict__ packed_out,
                 int N, int E, int NB, int GB, int EB) {
    __shared__ __align__(16) char shbuf[34816];

    const int t = threadIdx.x;
    const int tm = 2 * min(GB, EB);
    bool isg;
    int bid;
    if ((int)blockIdx.x < tm) {
        isg = !(blockIdx.x & 1);
        bid = blockIdx.x >> 1;
    } else {
        bid = (tm >> 1) + ((int)blockIdx.x - tm);
        isg = (GB > EB);
    }

    if (isg) {
        // ---------------- gemm1 role: 128 rows x 128 cols --------------------
        constexpr int K = KDIM;       // 128
        constexpr int KS = K + 8;     // 136
        constexpr int DOUT = 128;
        constexpr int NT = DOUT / 16; // 8
        _Float16* Wl = (_Float16*)shbuf;

        const int wave = t >> 6;
        const int lane = t & 63;
        const int l15 = lane & 15;
        const int quad = lane >> 4;

        // stage W (fp32 [K][DOUT] row-major) -> Wl fp16 n-major [n][k]
#pragma unroll
        for (int i = t; i < DOUT * (K / 4); i += 256) {
            int n = i & (DOUT - 1);
            int kg = i >> 7;       // 0..31
            union { _Float16 h[4]; uint2 u; } tmp;
#pragma unroll
            for (int j = 0; j < 4; j++)
                tmp.h[j] = (_Float16)W[(size_t)(kg * 4 + j) * DOUT + n];
            *(uint2*)(&Wl[n * KS + kg * 4]) = tmp.u;
        }
        __syncthreads();

        const int rowbase = bid * 128;
        const int row0 = rowbase + wave * 32 + l15;
        const int row1 = row0 + 16;
        const int rc0 = min(row0, N - 1);   // clamp: OOB A rows feed OOB D rows
        const int rc1 = min(row1, N - 1);

        f4v acc[2][NT];
#pragma unroll
        for (int r = 0; r < 2; r++)
#pragma unroll
            for (int ct = 0; ct < NT; ct++) acc[r][ct] = (f4v)0.0f;

#pragma unroll
        for (int kc = 0; kc < K; kc += 32) {
            const int kof = kc + quad * 8;
            const float* p0 = X + (size_t)rc0 * K + kof;
            const float* p1 = X + (size_t)rc1 * K + kof;
            h8 a0 = pack8(*(const float4*)p0, *(const float4*)(p0 + 4));
            h8 a1 = pack8(*(const float4*)p1, *(const float4*)(p1 + 4));
#pragma unroll
            for (int ct = 0; ct < NT; ct++) {
                h8 b = *(const h8*)(&Wl[(size_t)(ct * 16 + l15) * KS + kof]);
                acc[0][ct] = __builtin_amdgcn_mfma_f32_16x16x32_f16(a0, b, acc[0][ct], 0, 0, 0);
                acc[1][ct] = __builtin_amdgcn_mfma_f32_16x16x32_f16(a1, b, acc[1][ct], 0, 0, 0);
            }
        }

#pragma unroll
        for (int r = 0; r < 2; r++) {
            const int rb = rowbase + wave * 32 + r * 16 + quad * 4;
#pragma unroll
            for (int g = 0; g < 4; g++) {
                int row = rb + g;
                if (row < N) {
                    _Float16* op = outh + (size_t)row * DOUT + l15;
#pragma unroll
                    for (int ct = 0; ct < NT; ct++)
                        op[ct * 16] = (_Float16)acc[r][ct][g];   // unscaled
                }
            }
        }
    } else {
        // ---------------- bscatter role: 2048-edge chunk ---------------------
        int* lcnt = (int*)shbuf;                          // [256]
        int* lexc = lcnt + 256;                           // [256]
        int* lbase = lexc + 256;                          // [256]
        unsigned int* lpacked = (unsigned int*)(lbase + 256);        // [2048]
        unsigned char* lbslot = (unsigned char*)(lpacked + ECHUNK);  // [2048]
        int* wsumS = (int*)(lbslot + ECHUNK);                        // [4]

        const int lane = t & 63;

        lcnt[t] = 0;
        __syncthreads();

        const int base = bid * ECHUNK;
        const int cnt = min(ECHUNK, E - base);

#pragma unroll
        for (int j = 0; j < ECHUNK / 256; j++) {
            int e = base + j * 256 + t;
            if (e < E) atomicAdd(&lcnt[dst[e] >> BSHIFT], 1);
        }
        __syncthreads();

        // exclusive scan of lcnt via per-wave shuffle scan (2 barriers)
        int myc = lcnt[t];
        int incl = myc;
#pragma unroll
        for (int off = 1; off < 64; off <<= 1) {
            int x = __shfl_up(incl, off);
            if (lane >= off) incl += x;
        }
        if (lane == 63) wsumS[t >> 6] = incl;
        __syncthreads();
        if (t < 64) {
            int v = (t < 4) ? wsumS[t] : 0;
#pragma unroll
            for (int off = 1; off < 4; off <<= 1) {
                int x = __shfl_up(v, off);
                if (lane >= off) v += x;
            }
            if (t < 4) wsumS[t] = v;
        }
        __syncthreads();
        {
            int wp = (t >= 64) ? wsumS[(t >> 6) - 1] : 0;
            lexc[t] = incl + wp - myc;      // own slot only: safe
        }

        if (t < NB && lcnt[t]) lbase[t] = t * CAP + atomicAdd(&ecnt[t], lcnt[t]);
        __syncthreads();
        lcnt[t] = lexc[t];                      // local placement cursor
        __syncthreads();

#pragma unroll
        for (int j = 0; j < ECHUNK / 256; j++) {
            int e = base + j * 256 + t;
            if (e < E) {
                int d = dst[e];
                int b = d >> BSHIFT;
                int pos = atomicAdd(&lcnt[b], 1);
                lpacked[pos] = (unsigned int)src[e] | ((unsigned int)(d & (BSIZE - 1)) << PACK_SHIFT);
                lbslot[pos] = (unsigned char)b;
            }
        }
        __syncthreads();

#pragma unroll
        for (int j = 0; j < ECHUNK / 256; j++) {
            int s = j * 256 + t;
            if (s < cnt) {
                int b = lbslot[s];
                int pos = lbase[b] + (s - lexc[b]);
                if (pos < (b + 1) * CAP)        // overflow guard
                    packed_out[pos] = lpacked[s];
            }
        }
    }
}

// ---- per-bucket: degree count -> wave-scan -> rowptr/dinv -> place --------
// <1 block/CU (196 blocks): every barrier is latency-exposed. Wave-shuffle
// scans cut ~20 barriers to 5; the bucket-base prefix (ONE value) is a
// masked reduce on idle threads 512..767, concurrent with the degree scan.

__launch_bounds__(1024) __global__
void bfinal_kernel(const unsigned int* __restrict__ packed, const int* __restrict__ ecnt,
                   int* __restrict__ rowptr, float* __restrict__ dinv,
                   int* __restrict__ ssrc, int N, int E, int NB) {
    __shared__ int ncnt[BSIZE];
    __shared__ int wsum[8];
    __shared__ int redbuf[4];
    __shared__ int bbase_sh;

    const int t = threadIdx.x;
    const int b = blockIdx.x;
    const int lane = t & 63;

    if (t < BSIZE) ncnt[t] = 0;
    __syncthreads();                                    // barrier 1

    // load this bucket's packed run into registers + count node degrees
    const int cnt = min(ecnt[b], CAP);
    const unsigned int* pb = packed + (size_t)b * CAP;
    unsigned int held[CAP / 1024];
#pragma unroll
    for (int j = 0; j < CAP / 1024; j++) {
        int e = t + j * 1024;
        if (e < cnt) {
            unsigned int p = pb[e];
            held[j] = p;
            atomicAdd(&ncnt[p >> PACK_SHIFT], 1);
        }
    }
    __syncthreads();                                    // barrier 2

    // A: per-wave degree scan (t<512) || bucket-base reduce (512<=t<768)
    int mycnt = 0, incl = 0;
    if (t < BSIZE) {
        mycnt = ncnt[t];
        incl = mycnt;
#pragma unroll
        for (int off = 1; off < 64; off <<= 1) {
            int x = __shfl_up(incl, off);
            if (lane >= off) incl += x;
        }
        if (lane == 63) wsum[t >> 6] = incl;
    } else if (t < 768) {
        int i = t - 512;               // 0..255
        int v = (i < b && i < NB) ? min(ecnt[i], CAP) : 0;
#pragma unroll
        for (int off = 32; off > 0; off >>= 1) v += __shfl_down(v, off);
        if (lane == 0) redbuf[(t - 512) >> 6] = v;
    }
    __syncthreads();                                    // barrier 3

    // B: scan 8 wave totals (wave 0); sum 4 reduce partials (thread 512)
    if (t < 64) {
        int v = (t < 8) ? wsum[t] : 0;
#pragma unroll
        for (int off = 1; off < 8; off <<= 1) {
            int x = __shfl_up(v, off);
            if (lane >= off) v += x;
        }
        if (t < 8) wsum[t] = v;
    } else if (t == 512) {
        bbase_sh = redbuf[0] + redbuf[1] + redbuf[2] + redbuf[3];
    }
    __syncthreads();                                    // barrier 4

    const int gb = bbase_sh;
    if (t < BSIZE) {
        int wp = (t >= 64) ? wsum[(t >> 6) - 1] : 0;
        int exc = incl + wp - mycnt;                    // exclusive degree scan
        int node = (b << BSHIFT) + t;
        if (node < N) {
            rowptr[node] = gb + exc;
            dinv[node] = rsqrtf((float)(mycnt + 1));    // +1 self loop
        }
        ncnt[t] = gb + exc;                             // placement cursor
    }
    if (t == 0 && b == NB - 1) rowptr[N] = gb + cnt;
    __syncthreads();                                    // barrier 5

    // placement from registers; ssrc window ~33 KB -> L2-resident
#pragma unroll
    for (int j = 0; j < CAP / 1024; j++) {
        int e = t + j * 1024;
        if (e < cnt) {
            unsigned int p = held[j];
            int d = p >> PACK_SHIFT;
            int pos = atomicAdd(&ncnt[d], 1);
            ssrc[pos] = (int)(p & PACK_MASK);
        }
    }
}

// ---- FUSED layer-1 aggregation + layer-2 GEMM (barrier-free GEMM) ---------
// hs1 is UNSCALED; source scaling applied at gather via fmac (same inst
// count); self-loop = di^2 * h_i via acc-init. R2-proven LDS layout
// (KS=136 pad, no swizzle). ssrc scalar loads (R8: dwordx4 regressed).

__launch_bounds__(512, 8) __global__
void agg_gemm_kernel(const __half* __restrict__ hs, const int* __restrict__ rowptr,
                     const int* __restrict__ ssrc, const float* __restrict__ dinv,
                     const float* __restrict__ bias, const float* __restrict__ W2,
                     _Float16* __restrict__ hs2, int N) {
    constexpr int K = KDIM;       // 128 (layer-1 width = GEMM K)
    constexpr int KS = K + 8;     // 136-half pad stride (16B aligned)
    constexpr int DO2 = 64;       // layer-2 width
    __shared__ _Float16 W2l[DO2 * KS];      // 17.4 KB, n-major fp16
    __shared__ _Float16 o_lds[8][4 * KS];   //  8.7 KB, 4 rows per wave

    const int t = threadIdx.x;

    // stage W2 (fp32 [128][64] row-major) -> fp16 n-major [n][k]
#pragma unroll
    for (int i = t; i < DO2 * (K / 4); i += 512) {
        int n = i & (DO2 - 1);
        int kg = i >> 6;           // 0..31
        union { _Float16 h[4]; uint2 u; } tmp;
#pragma unroll
        for (int j = 0; j < 4; j++)
            tmp.h[j] = (_Float16)W2[(size_t)(kg * 4 + j) * DO2 + n];
        *(uint2*)(&W2l[n * KS + kg * 4]) = tmp.u;
    }
    __syncthreads();               // ONLY block barrier: uniform cost, pre-gather

    // ---- phase 1: gather-aggregate (16 lanes/node, 4 nodes/wave) ----------
    const int nl = t >> 4;                 // node slot 0..31
    const int node = blockIdx.x * 32 + nl;
    const int flane = t & 15;
    const int c0 = flane * 8;

    h8 oh;
    if (node < N) {
        const float di = dinv[node];
        float acc[8];
        {
            uint4 u = *(const uint4*)(hs + (size_t)node * K + c0);  // self loop
            const __half2* hp = (const __half2*)&u;
#pragma unroll
            for (int q = 0; q < 4; q++) {
                float2 f = __half22float2(hp[q]);
                acc[2 * q]     = di * f.x;          // self: di^2*h_i after final *di
                acc[2 * q + 1] = di * f.y;
            }
        }

        const int e0 = rowptr[node];
        const int e1 = rowptr[node + 1];
        int e = e0;
        for (; e + 4 <= e1; e += 4) {
            int s0 = ssrc[e + 0];
            int s1 = ssrc[e + 1];
            int s2 = ssrc[e + 2];
            int s3 = ssrc[e + 3];
            float d0 = dinv[s0];
            float d1 = dinv[s1];
            float d2 = dinv[s2];
            float d3 = dinv[s3];
            uint4 u0 = *(const uint4*)(hs + (size_t)s0 * K + c0);
            uint4 u1 = *(const uint4*)(hs + (size_t)s1 * K + c0);
            uint4 u2 = *(const uint4*)(hs + (size_t)s2 * K + c0);
            uint4 u3 = *(const uint4*)(hs + (size_t)s3 * K + c0);
            const __half2* p0 = (const __half2*)&u0;
            const __half2* p1 = (const __half2*)&u1;
            const __half2* p2 = (const __half2*)&u2;
            const __half2* p3 = (const __half2*)&u3;
#pragma unroll
            for (int q = 0; q < 4; q++) {
                float2 f0 = __half22float2(p0[q]);
                float2 f1 = __half22float2(p1[q]);
                float2 f2 = __half22float2(p2[q]);
                float2 f3 = __half22float2(p3[q]);
                acc[2 * q]     += d0 * f0.x + d1 * f1.x + d2 * f2.x + d3 * f3.x;
                acc[2 * q + 1] += d0 * f0.y + d1 * f1.y + d2 * f2.y + d3 * f3.y;
            }
        }
        for (; e < e1; e++) {
            int s = ssrc[e];
            float ds = dinv[s];
            uint4 u = *(const uint4*)(hs + (size_t)s * K + c0);
            const __half2* hp = (const __half2*)&u;
#pragma unroll
            for (int q = 0; q < 4; q++) {
                float2 f = __half22float2(hp[q]);
                acc[2 * q]     += ds * f.x;
                acc[2 * q + 1] += ds * f.y;
            }
        }

#pragma unroll
        for (int q = 0; q < 2; q++) {
            float4 bq = *(const float4*)(bias + c0 + 4 * q);
            oh[4 * q + 0] = (_Float16)fmaxf(di * acc[4 * q + 0] + bq.x, 0.f);
            oh[4 * q + 1] = (_Float16)fmaxf(di * acc[4 * q + 1] + bq.y, 0.f);
            oh[4 * q + 2] = (_Float16)fmaxf(di * acc[4 * q + 2] + bq.z, 0.f);
            oh[4 * q + 3] = (_Float16)fmaxf(di * acc[4 * q + 3] + bq.w, 0.f);
        }
    } else {
#pragma unroll
        for (int j = 0; j < 8; j++) oh[j] = (_Float16)0.f;
    }

    // ---- phase 2: wave-local transpose + 16x64x128 MFMA (no block barrier)
    const int wv = t >> 6;
    const int a = (t >> 4) & 3;            // node slot within wave (row 0..3)
    *(h8*)(&o_lds[wv][a * KS + c0]) = oh;
    asm volatile("s_waitcnt lgkmcnt(0)" ::: "memory");   // wave-local ordering
    __builtin_amdgcn_sched_barrier(0);

    const int lane = t & 63;
    const int l15 = lane & 15;
    const int quad = lane >> 4;

    f4v acc2[4];
#pragma unroll
    for (int ct = 0; ct < 4; ct++) acc2[ct] = (f4v)0.0f;

#pragma unroll
    for (int kc = 0; kc < K; kc += 32) {
        const int kof = kc + quad * 8;
        // A rows 4-15 duplicate rows 0-3 -> duplicate D rows, discarded
        h8 afr = *(const h8*)(&o_lds[wv][(l15 & 3) * KS + kof]);
#pragma unroll
        for (int ct = 0; ct < 4; ct++) {
            h8 b = *(const h8*)(&W2l[(size_t)(ct * 16 + l15) * KS + kof]);
            acc2[ct] = __builtin_amdgcn_mfma_f32_16x16x32_f16(afr, b, acc2[ct], 0, 0, 0);
        }
    }

    // quad q holds rows q*4+g = node (g) content (dup rows) -> write tile q.
    f4v av = (quad == 0) ? acc2[0] : (quad == 1) ? acc2[1]
           : (quad == 2) ? acc2[2] : acc2[3];
    const int rowbase = blockIdx.x * 32 + wv * 4;
#pragma unroll
    for (int g = 0; g < 4; g++) {
        int r = rowbase + g;
        if (r < N)
            hs2[(size_t)r * DO2 + quad * 16 + l15] = (_Float16)(av[g] * dinv[r]);
    }
}

// ---- Aggregation: out[i] = act(dinv[i]*(sum_e hs[src[e]] + hs[i]) + b) ----
// hs fp16 (pre-scaled by source dinv); TPN = DOUT/8 lanes/node; unroll-4.

template <int DOUT, bool RELU, bool HOUT>
__launch_bounds__(256) __global__
void agg_kernel(const __half* __restrict__ hs, const int* __restrict__ rowptr,
                const int* __restrict__ ssrc, const float* __restrict__ dinv,
                const float* __restrict__ bias, void* __restrict__ outv, int N) {
    constexpr int TPN = DOUT / 8;
    const int npb = blockDim.x / TPN;
    const int node = blockIdx.x * npb + threadIdx.x / TPN;
    if (node >= N) return;
    const int lane = threadIdx.x % TPN;
    const int c0 = lane * 8;

    float acc[8];
    {
        uint4 u = *(const uint4*)(hs + (size_t)node * DOUT + c0);  // self loop
        const __half2* hp = (const __half2*)&u;
#pragma unroll
        for (int q = 0; q < 4; q++) {
            float2 f = __half22float2(hp[q]);
            acc[2 * q] = f.x;
            acc[2 * q + 1] = f.y;
        }
    }

    const int e0 = rowptr[node];
    const int e1 = rowptr[node + 1];
    int e = e0;
    for (; e + 4 <= e1; e += 4) {
        int s0 = ssrc[e + 0];
        int s1 = ssrc[e + 1];
        int s2 = ssrc[e + 2];
        int s3 = ssrc[e + 3];
        uint4 u0 = *(const uint4*)(hs + (size_t)s0 * DOUT + c0);
        uint4 u1 = *(const uint4*)(hs + (size_t)s1 * DOUT + c0);
        uint4 u2 = *(const uint4*)(hs + (size_t)s2 * DOUT + c0);
        uint4 u3 = *(const uint4*)(hs + (size_t)s3 * DOUT + c0);
        const __half2* p0 = (const __half2*)&u0;
        const __half2* p1 = (const __half2*)&u1;
        const __half2* p2 = (const __half2*)&u2;
        const __half2* p3 = (const __half2*)&u3;
#pragma unroll
        for (int q = 0; q < 4; q++) {
            float2 f0 = __half22float2(p0[q]);
            float2 f1 = __half22float2(p1[q]);
            float2 f2 = __half22float2(p2[q]);
            float2 f3 = __half22float2(p3[q]);
            acc[2 * q]     += (f0.x + f1.x) + (f2.x + f3.x);
            acc[2 * q + 1] += (f0.y + f1.y) + (f2.y + f3.y);
        }
    }
    for (; e < e1; e++) {
        int s = ssrc[e];
        uint4 u = *(const uint4*)(hs + (size_t)s * DOUT + c0);
        const __half2* hp = (const __half2*)&u;
#pragma unroll
        for (int q = 0; q < 4; q++) {
            float2 f = __half22float2(hp[q]);
            acc[2 * q] += f.x;
            acc[2 * q + 1] += f.y;
        }
    }

    const float di = dinv[node];
    float o[8];
#pragma unroll
    for (int q = 0; q < 2; q++) {
        float4 bq = *(const float4*)(bias + c0 + 4 * q);
        o[4 * q + 0] = di * acc[4 * q + 0] + bq.x;
        o[4 * q + 1] = di * acc[4 * q + 1] + bq.y;
        o[4 * q + 2] = di * acc[4 * q + 2] + bq.z;
        o[4 * q + 3] = di * acc[4 * q + 3] + bq.w;
    }
    if (RELU) {
#pragma unroll
        for (int j = 0; j < 8; j++) o[j] = fmaxf(o[j], 0.f);
    }
    if (HOUT) {
        union { __half2 h[4]; uint4 u; } pk;
#pragma unroll
        for (int q = 0; q < 4; q++)
            pk.h[q] = __floats2half2_rn(o[2 * q], o[2 * q + 1]);
        *(uint4*)((__half*)outv + (size_t)node * DOUT + c0) = pk.u;
    } else {
        float* op = (float*)outv + (size_t)node * DOUT + c0;
        *(float4*)op = make_float4(o[0], o[1], o[2], o[3]);
        *(float4*)(op + 4) = make_float4(o[4], o[5], o[6], o[7]);
    }
}

// ---------------------------------------------------------------------------

extern "C" void kernel_launch(void* const* d_in, const int* in_sizes, int n_in,
                              void* d_out, int out_size, void* d_ws, size_t ws_size,
                              hipStream_t stream) {
    const float* x  = (const float*)d_in[0];
    const int*   ei = (const int*)d_in[1];
    const float* W1 = (const float*)d_in[3];
    const float* b1 = (const float*)d_in[4];
    const float* W2 = (const float*)d_in[5];
    const float* b2 = (const float*)d_in[6];
    float* out = (float*)d_out;

    const int N = in_sizes[0] / KDIM;  // 100000
    const int E = in_sizes[1] / 2;     // 1600000
    const int* esrc = ei;
    const int* edst = ei + E;
    const int NB = (N + BSIZE - 1) >> BSHIFT;  // 196

    char* ws = (char*)d_ws;
    size_t off = 0;
    auto alloc = [&](size_t bytes) {
        size_t p = off;
        off = (off + bytes + 511) & ~(size_t)511;
        return p;
    };
    int*      ecnt    = (int*)(ws + alloc((size_t)NB * 4));
    int*      rowptr  = (int*)(ws + alloc((size_t)(N + 1) * 4));
    float*    dinv    = (float*)(ws + alloc((size_t)N * 4));
    int*      ssrc    = (int*)(ws + alloc((size_t)E * 4));
    _Float16* hs1     = (_Float16*)(ws + alloc((size_t)N * KDIM * 2));  // fp16 layer-1 pre-agg
    _Float16* hs2     = (_Float16*)(ws + alloc((size_t)N * 64 * 2));    // fp16 layer-2 pre-agg
    // packed aliases hs2 (NB*CAP*4 = 8.0MB <= 12.8MB): written by bscatter
    // role, consumed by bfinal, then hs2 overwritten by agg_gemm. gemm1 role
    // writes hs1 concurrently -- DISJOINT from hs2.
    unsigned int* packed = (unsigned int*)hs2;
    (void)ws_size; (void)n_in; (void)out_size;

    const int eb = (E + ECHUNK - 1) / ECHUNK;   // 782
    const int gb = (N + 127) / 128;             // 782

    hipMemsetAsync(ecnt, 0, (size_t)NB * 4, stream);

    // gemm1 (hs1 = fp16(X@W1), unscaled) || bscatter -- data-independent
    prep_kernel<<<gb + eb, 256, 0, stream>>>(x, W1, hs1, esrc, edst, ecnt,
                                             packed, N, E, NB, gb, eb);
    bfinal_kernel<<<NB, 1024, 0, stream>>>(packed, ecnt, rowptr, dinv, ssrc, N, E, NB);

    // FUSED: agg1 (relu, dinv at gather) + per-wave gemm2 -> hs2
    agg_gemm_kernel<<<(N + 31) / 32, 512, 0, stream>>>(
        (const __half*)hs1, rowptr, ssrc, dinv, b1, W2, hs2, N);

    // layer 2 aggregation: out = dinv*(gather+self) + b2
    agg_kernel<64, false, false><<<(N + 31) / 32, 256, 0, stream>>>(
        (const __half*)hs2, rowptr, ssrc, dinv, b2, out, N);
}